// Round 5
// baseline (658.395 us; speedup 1.0000x reference)
//
#include <hip/hip_runtime.h>
#include <hip/hip_bf16.h>

typedef __attribute__((ext_vector_type(8))) short bf16x8;
typedef __attribute__((ext_vector_type(4))) float f32x4;
typedef __attribute__((ext_vector_type(4))) unsigned u32x4;

#define CDIM 1024
#define DDIM 1024
#define TDIM 1024
#define BK 32

__device__ __forceinline__ unsigned cvt_pk_bf16(float a, float b) {
    unsigned r;
    asm("v_cvt_pk_bf16_f32 %0, %1, %2" : "=v"(r) : "v"(a), "v"(b));
    return r;
}

// out[b,d,t] = sum_c x[b,c,t] * w[subj[b],c,d]
// 128(d) x 128(t) tile / block, 4 waves each 64x64, bf16x3 split precision.
// LDS row = d (or t), 8 granules x 8 shorts: g0-3 = hi(k0..31), g4-7 = lo.
// Granule slot XOR-swizzled with swz(row) = (row ^ row>>3) & 7:
//   - staging writes: quarter-wave rows step by 4 -> swz spans all 8 slots
//     (row&7 alone gave 2 slots -> 8-way conflict -> the round-4 1e8-cycle hit)
//   - frag reads: rows step by 1 -> swz spans all 8 slots. Both 2-way = free.
__global__ __launch_bounds__(256, 4)
void subject_gemm(const float* __restrict__ x, const int* __restrict__ subj,
                  const float* __restrict__ w, float* __restrict__ out)
{
    __shared__ short Wt[128 * 64];
    __shared__ short Xt[128 * 64];

    // XCD-aware mapping: blocks dispatch round-robin over 8 XCDs (bid&7).
    // 8 whole batches per XCD; ttile fastest so consecutive slots share W panel.
    const int bid = blockIdx.x;
    const int xcd = bid & 7;
    const int slot = bid >> 3;               // 0..511 per XCD
    const int b = (xcd << 3) | (slot >> 6);  // 8 batches per XCD
    const int r = slot & 63;
    const int dtile = (r >> 3) << 7;
    const int ttile = (r & 7) << 7;

    const int s = subj[b];
    const float* __restrict__ wB = w + (size_t)s * (CDIM * DDIM);
    const float* __restrict__ xB = x + (size_t)b * (CDIM * TDIM);

    const int tid = threadIdx.x;
    const int lane = tid & 63;
    const int wave = tid >> 6;

    // ---- staging role: waves 0,1 stage W; waves 2,3 stage X ----
    const int ht = tid & 127;
    const int tq = ht & 31;            // column-quad index
    const int cg = ht >> 5;            // k-granule 0..3 (8 c's each)
    const int col0 = tq << 2;
    const bool isW = (tid < 128);
    const float* sp = (isW ? wB + dtile : xB + ttile) + col0;
    short* slds = (isW ? Wt : Xt);

    // ---- fragment assignment ----
    const int wr = (wave >> 1) << 6;   // wave d offset: 0/64
    const int wc = (wave & 1) << 6;    // wave t offset: 0/64
    const int fr = lane & 15;
    const int fg = lane >> 4;          // k-granule 0..3

    // per-subtile swizzled fragment offsets (shorts)
    int offHW[4], offLW[4], offHX[4], offLX[4];
    #pragma unroll
    for (int m = 0; m < 4; ++m) {
        const int rowW = wr + m * 16 + fr;
        const int sw = (rowW ^ (rowW >> 3)) & 7;
        offHW[m] = ((fg ^ sw) << 3);
        offLW[m] = (((fg + 4) ^ sw) << 3);
        const int rowX = wc + m * 16 + fr;
        const int sx = (rowX ^ (rowX >> 3)) & 7;
        offHX[m] = ((fg ^ sx) << 3);
        offLX[m] = (((fg + 4) ^ sx) << 3);
    }

    f32x4 acc[4][4] = {};

    for (int k0 = 0; k0 < CDIM; k0 += BK) {
        // 8x float4 column-block load: rows c = k0+cg*8+j, cols col0..col0+3
        float4 v4[8];
        #pragma unroll
        for (int j = 0; j < 8; ++j) {
            const int c = k0 + (cg << 3) + j;
            v4[j] = *(const float4*)(sp + ((size_t)c << 10));
        }

        // split-convert: per output row rr (4 rows), pack 8 c's -> hi/lo b128
        u32x4 hg[4], lg[4];
        #pragma unroll
        for (int rr = 0; rr < 4; ++rr) {
            #pragma unroll
            for (int p = 0; p < 4; ++p) {
                const float f0 = v4[2 * p][rr];
                const float f1 = v4[2 * p + 1][rr];
                const unsigned h = cvt_pk_bf16(f0, f1);
                const float l0 = f0 - __uint_as_float(h << 16);
                const float l1 = f1 - __uint_as_float(h & 0xFFFF0000u);
                hg[rr][p] = h;
                lg[rr][p] = cvt_pk_bf16(l0, l1);
            }
        }

        __syncthreads();   // previous iteration's frag reads complete
        #pragma unroll
        for (int rr = 0; rr < 4; ++rr) {
            const int row = col0 + rr;
            short* sl = slds + row * 64;
            const int swz = (row ^ (row >> 3)) & 7;
            *(u32x4*)(sl + ((cg ^ swz) << 3)) = hg[rr];
            *(u32x4*)(sl + (((cg + 4) ^ swz) << 3)) = lg[rr];
        }
        __syncthreads();   // tile staged

        // B-frags resident (X), A-frags (W) per-m to bound VGPR pressure
        bf16x8 bh[4], bl[4];
        #pragma unroll
        for (int n = 0; n < 4; ++n) {
            const short* xrow = Xt + (wc + n * 16 + fr) * 64;
            bh[n] = *(const bf16x8*)(xrow + offHX[n]);
            bl[n] = *(const bf16x8*)(xrow + offLX[n]);
        }
        #pragma unroll
        for (int m = 0; m < 4; ++m) {
            const short* wrow = Wt + (wr + m * 16 + fr) * 64;
            const bf16x8 ah = *(const bf16x8*)(wrow + offHW[m]);
            const bf16x8 al = *(const bf16x8*)(wrow + offLW[m]);
            #pragma unroll
            for (int n = 0; n < 4; ++n) {
                acc[m][n] = __builtin_amdgcn_mfma_f32_16x16x32_bf16(ah, bh[n], acc[m][n], 0, 0, 0);
                acc[m][n] = __builtin_amdgcn_mfma_f32_16x16x32_bf16(ah, bl[n], acc[m][n], 0, 0, 0);
                acc[m][n] = __builtin_amdgcn_mfma_f32_16x16x32_bf16(al, bh[n], acc[m][n], 0, 0, 0);
            }
        }
    }

    // epilogue: C/D layout col = lane&15 (t), row = (lane>>4)*4 + q (d)
    float* __restrict__ oB = out + (size_t)b * (DDIM * TDIM)
                           + (size_t)(dtile + wr) * TDIM + (ttile + wc);
    #pragma unroll
    for (int m = 0; m < 4; ++m) {
        #pragma unroll
        for (int n = 0; n < 4; ++n) {
            #pragma unroll
            for (int q = 0; q < 4; ++q) {
                const int d = m * 16 + (fg << 2) + q;
                const int t = n * 16 + fr;
                oB[d * TDIM + t] = acc[m][n][q];
            }
        }
    }
}

extern "C" void kernel_launch(void* const* d_in, const int* in_sizes, int n_in,
                              void* d_out, int out_size, void* d_ws, size_t ws_size,
                              hipStream_t stream) {
    const float* x = (const float*)d_in[0];
    const int* subjects = (const int*)d_in[1];
    const float* w = (const float*)d_in[2];
    float* out = (float*)d_out;
    subject_gemm<<<dim3(64 * 8 * 8), dim3(256), 0, stream>>>(x, subjects, w, out);
}

// Round 6
// 444.128 us; speedup vs baseline: 1.4824x; 1.4824x over previous
//
#include <hip/hip_runtime.h>
#include <hip/hip_bf16.h>

typedef __attribute__((ext_vector_type(8))) short bf16x8;
typedef __attribute__((ext_vector_type(4))) float f32x4;
typedef __attribute__((ext_vector_type(4))) unsigned u32x4;

#define CDIM 1024
#define DDIM 1024
#define TDIM 1024
#define BK 32

__device__ __forceinline__ unsigned cvt_pk_bf16(float a, float b) {
    unsigned r;
    asm("v_cvt_pk_bf16_f32 %0, %1, %2" : "=v"(r) : "v"(a), "v"(b));
    return r;
}

// out[b,d,t] = sum_c x[b,c,t] * w[subj[b],c,d]
// 128(d) x 128(t) tile / block, 4 waves each 64x64, bf16x3 split precision.
// LDS row = d (or t), 8 granules x 8 shorts: g0-3 = hi(k0..31), g4-7 = lo.
// Granule slot XOR-swizzled with swz(row) = (row ^ row>>3) & 7 (write rows
// step by 4, read rows by 1 -> both span all 8 slots -> 2-way = free).
// T14 pipeline: global->reg loads for tile k+1 issued before converting
// tile k (two named buffers, explicit 2x-unrolled body — rule #20).
// __launch_bounds__(256,2): ILP-based hiding, low L2 co-residency.

#define KSTEP(VCUR, VNXT, K0)                                                   \
  {                                                                             \
    const int kn = (K0) + BK;                                                   \
    const int ksafe = kn & (CDIM - 1);   /* last iter: harmless re-read of 0 */ \
    _Pragma("unroll")                                                           \
    for (int j = 0; j < 8; ++j)                                                 \
        VNXT[j] = *(const float4*)(sp + ((size_t)(ksafe + (cg << 3) + j) << 10)); \
    u32x4 hg[4], lg[4];                                                         \
    _Pragma("unroll")                                                           \
    for (int rr = 0; rr < 4; ++rr) {                                            \
      _Pragma("unroll")                                                         \
      for (int p = 0; p < 4; ++p) {                                             \
        const float f0 = VCUR[2 * p][rr];                                       \
        const float f1 = VCUR[2 * p + 1][rr];                                   \
        const unsigned h = cvt_pk_bf16(f0, f1);                                 \
        const float l0 = f0 - __uint_as_float(h << 16);                         \
        const float l1 = f1 - __uint_as_float(h & 0xFFFF0000u);                 \
        hg[rr][p] = h;                                                          \
        lg[rr][p] = cvt_pk_bf16(l0, l1);                                        \
      }                                                                         \
    }                                                                           \
    __syncthreads();                                                            \
    _Pragma("unroll")                                                           \
    for (int rr = 0; rr < 4; ++rr) {                                            \
      const int row = col0 + rr;                                                \
      short* sl = slds + row * 64;                                              \
      const int swz = (row ^ (row >> 3)) & 7;                                   \
      *(u32x4*)(sl + ((cg ^ swz) << 3)) = hg[rr];                               \
      *(u32x4*)(sl + (((cg + 4) ^ swz) << 3)) = lg[rr];                         \
    }                                                                           \
    __syncthreads();                                                            \
    bf16x8 bh[4], bl[4];                                                        \
    _Pragma("unroll")                                                           \
    for (int n = 0; n < 4; ++n) {                                               \
      const short* xrow = Xt + (wc + n * 16 + fr) * 64;                         \
      bh[n] = *(const bf16x8*)(xrow + offHX[n]);                                \
      bl[n] = *(const bf16x8*)(xrow + offLX[n]);                                \
    }                                                                           \
    _Pragma("unroll")                                                           \
    for (int m = 0; m < 4; ++m) {                                               \
      const short* wrow = Wt + (wr + m * 16 + fr) * 64;                         \
      const bf16x8 ah = *(const bf16x8*)(wrow + offHW[m]);                      \
      const bf16x8 al = *(const bf16x8*)(wrow + offLW[m]);                      \
      _Pragma("unroll")                                                         \
      for (int n = 0; n < 4; ++n) {                                             \
        acc[m][n] = __builtin_amdgcn_mfma_f32_16x16x32_bf16(ah, bh[n], acc[m][n], 0, 0, 0); \
        acc[m][n] = __builtin_amdgcn_mfma_f32_16x16x32_bf16(ah, bl[n], acc[m][n], 0, 0, 0); \
        acc[m][n] = __builtin_amdgcn_mfma_f32_16x16x32_bf16(al, bh[n], acc[m][n], 0, 0, 0); \
      }                                                                         \
    }                                                                           \
  }

__global__ __launch_bounds__(256, 2)
void subject_gemm(const float* __restrict__ x, const int* __restrict__ subj,
                  const float* __restrict__ w, float* __restrict__ out)
{
    __shared__ short Wt[128 * 64];
    __shared__ short Xt[128 * 64];

    // XCD-aware mapping: blocks round-robin over 8 XCDs (bid&7).
    // 8 whole batches per XCD; ttile fastest so consecutive slots share W panel.
    const int bid = blockIdx.x;
    const int xcd = bid & 7;
    const int slot = bid >> 3;               // 0..511 per XCD
    const int b = (xcd << 3) | (slot >> 6);  // 8 batches per XCD
    const int r = slot & 63;
    const int dtile = (r >> 3) << 7;
    const int ttile = (r & 7) << 7;

    const int s = subj[b];
    const float* __restrict__ wB = w + (size_t)s * (CDIM * DDIM);
    const float* __restrict__ xB = x + (size_t)b * (CDIM * TDIM);

    const int tid = threadIdx.x;
    const int lane = tid & 63;
    const int wave = tid >> 6;

    // ---- staging role: waves 0,1 stage W; waves 2,3 stage X ----
    const int ht = tid & 127;
    const int tq = ht & 31;            // column-quad index
    const int cg = ht >> 5;            // k-granule 0..3 (8 c's each)
    const int col0 = tq << 2;
    const bool isW = (tid < 128);
    const float* sp = (isW ? wB + dtile : xB + ttile) + col0;
    short* slds = (isW ? Wt : Xt);

    // ---- fragment assignment ----
    const int wr = (wave >> 1) << 6;   // wave d offset: 0/64
    const int wc = (wave & 1) << 6;    // wave t offset: 0/64
    const int fr = lane & 15;
    const int fg = lane >> 4;          // k-granule 0..3

    // per-subtile swizzled fragment offsets (shorts)
    int offHW[4], offLW[4], offHX[4], offLX[4];
    #pragma unroll
    for (int m = 0; m < 4; ++m) {
        const int rowW = wr + m * 16 + fr;
        const int sw = (rowW ^ (rowW >> 3)) & 7;
        offHW[m] = ((fg ^ sw) << 3);
        offLW[m] = (((fg + 4) ^ sw) << 3);
        const int rowX = wc + m * 16 + fr;
        const int sx = (rowX ^ (rowX >> 3)) & 7;
        offHX[m] = ((fg ^ sx) << 3);
        offLX[m] = (((fg + 4) ^ sx) << 3);
    }

    f32x4 acc[4][4] = {};

    // prologue: load tile 0
    float4 va[8], vb[8];
    #pragma unroll
    for (int j = 0; j < 8; ++j)
        va[j] = *(const float4*)(sp + ((size_t)((cg << 3) + j) << 10));

    for (int k0 = 0; k0 < CDIM; k0 += 2 * BK) {
        KSTEP(va, vb, k0);
        KSTEP(vb, va, k0 + BK);
    }

    // epilogue: C/D layout col = lane&15 (t), row = (lane>>4)*4 + q (d).
    // Loop order (m,q,n): 4 consecutive stores fill one row's 256B segment
    // -> full-line writes, avoid HBM read-modify-write.
    float* __restrict__ oB = out + (size_t)b * (DDIM * TDIM)
                           + (size_t)(dtile + wr) * TDIM + (ttile + wc);
    #pragma unroll
    for (int m = 0; m < 4; ++m) {
        #pragma unroll
        for (int q = 0; q < 4; ++q) {
            const int d = m * 16 + (fg << 2) + q;
            float* orow = oB + (size_t)d * TDIM;
            #pragma unroll
            for (int n = 0; n < 4; ++n) {
                orow[n * 16 + fr] = acc[m][n][q];
            }
        }
    }
}

extern "C" void kernel_launch(void* const* d_in, const int* in_sizes, int n_in,
                              void* d_out, int out_size, void* d_ws, size_t ws_size,
                              hipStream_t stream) {
    const float* x = (const float*)d_in[0];
    const int* subjects = (const int*)d_in[1];
    const float* w = (const float*)d_in[2];
    float* out = (float*)d_out;
    subject_gemm<<<dim3(64 * 8 * 8), dim3(256), 0, stream>>>(x, subjects, w, out);
}